// Round 21
// baseline (2512.242 us; speedup 1.0000x reference)
//
#include <hip/hip_runtime.h>
#include <math.h>

#define VOCAB 50000
#define DM 256
#define NB 8
#define NK 4
#define SL 24
#define NROW 32
#define CBLK 256         // columns per logits block (4 per lane)
#define NXB 196          // ceil(50000/256)
#define NPART NXB        // lse partials per row
#define DIVS 0.5f
#define NCH 49           // selection chunks of 1024 per row
#define SCH 1024
#define CINV 0x7fffffff

__device__ __forceinline__ bool cbetter(float av, int ai, float bv, int bi) {
  return (av > bv) || (av == bv && ai < bi);
}

// merge two sorted-4 lists by (key desc, idx asc); idx passed explicitly
__device__ __forceinline__ void merge4(const float* av, const int* ai,
                                       const float* bv, const int* bi,
                                       float* rv, int* ri) {
  int x = 0, y = 0;
#pragma unroll
  for (int j = 0; j < 4; ++j) {
    bool ta = cbetter(av[x], ai[x], bv[y], bi[y]);
    rv[j] = ta ? av[x] : bv[y];
    ri[j] = ta ? ai[x] : bi[y];
    if (ta) ++x; else ++y;
  }
}

// same but payload carries pen bit in bit16: compare on col = payload & 0xFFFF
__device__ __forceinline__ void merge4c(const float* av, const int* ai,
                                        const float* bv, const int* bi,
                                        float* rv, int* ri) {
  int x = 0, y = 0;
#pragma unroll
  for (int j = 0; j < 4; ++j) {
    bool ta = cbetter(av[x], ai[x] & 0xFFFF, bv[y], bi[y] & 0xFFFF);
    rv[j] = ta ? av[x] : bv[y];
    ri[j] = ta ? ai[x] : bi[y];
    if (ta) ++x; else ++y;
  }
}

// ctx[b][d] = mean_s(src[b,s,:]) @ We
__global__ void k_prep(const float* __restrict__ src, const float* __restrict__ We,
                       float* __restrict__ ctx) {
  int b = blockIdx.x, d = threadIdx.x;
  __shared__ float sm[DM];
  const float* p = src + (size_t)b * 128 * DM + d;
  float s = 0.f;
  for (int i = 0; i < 128; ++i) s += p[i * DM];
  sm[d] = s * (1.f / 128.f);
  __syncthreads();
  float acc = 0.f;
  for (int dp = 0; dp < DM; ++dp) acc += sm[dp] * We[dp * DM + d];
  ctx[b * DM + d] = acc;
}

// eg[r][d] = Emb[tok_r][d] + ctx[r/4][d]   (t==1 only; s2 updates eg after)
__global__ void k_eprep(const float* __restrict__ Emb, const float* __restrict__ ctx,
                        const int* __restrict__ seq, float* __restrict__ eg, int t) {
  int r = blockIdx.x, d = threadIdx.x;
  int tok = seq[r * SL + (t - 1)];
  eg[r * DM + d] = Emb[(size_t)tok * DM + d] + ctx[(r >> 2) * DM + d];
}

// One-time per launch: tile Wout so each logits block reads a CONTIGUOUS
// 256-KB region. WT[b][d][c] = Wout[d][b*256+c] (0 beyond VOCAB).
__global__ void k_wtile(const float* __restrict__ Wout, float* __restrict__ WT) {
  int b = blockIdx.x, d = blockIdx.y, c = threadIdx.x;
  int col = b * CBLK + c;
  WT[(size_t)b * (CBLK * DM) + d * CBLK + c] =
      (col < VOCAB) ? Wout[(size_t)d * VOCAB + col] : 0.f;
}

// r20 tiled logits kernel (verbatim)
__global__ __launch_bounds__(512) void k_logits_tiled(
    const float* __restrict__ WT, const float* __restrict__ eg,
    float* __restrict__ logits, float* __restrict__ pm, float* __restrict__ ps) {
  int tid = threadIdx.x;
  int lane = tid & 63, wq = tid >> 6;
  int c0 = blockIdx.x * CBLK + lane * 4;
  bool valid = (c0 + 3 < VOCAB);
  const float* wbase = WT + (size_t)blockIdx.x * (CBLK * DM) + lane * 4;
  int rb = __builtin_amdgcn_readfirstlane(wq) * 4;
  const float* e0 = eg + (size_t)rb * DM;
  float acc[4][4];
#pragma unroll
  for (int r = 0; r < 4; ++r)
#pragma unroll
    for (int c = 0; c < 4; ++c) acc[r][c] = 0.f;

  for (int d = 0; d < DM; d += 8) {
    float4 w[8];
#pragma unroll
    for (int j = 0; j < 8; ++j)
      w[j] = *reinterpret_cast<const float4*>(wbase + (size_t)(d + j) * CBLK);
#pragma unroll
    for (int r = 0; r < 4; ++r) {
      const float* ep = e0 + r * DM + d;
      const float4 ea = *reinterpret_cast<const float4*>(ep);
      const float4 eb = *reinterpret_cast<const float4*>(ep + 4);
#pragma unroll
      for (int c = 0; c < 4; ++c) {
        float a = acc[r][c];
        a = fmaf(ea.x, (&w[0].x)[c], a);
        a = fmaf(ea.y, (&w[1].x)[c], a);
        a = fmaf(ea.z, (&w[2].x)[c], a);
        a = fmaf(ea.w, (&w[3].x)[c], a);
        a = fmaf(eb.x, (&w[4].x)[c], a);
        a = fmaf(eb.y, (&w[5].x)[c], a);
        a = fmaf(eb.z, (&w[6].x)[c], a);
        a = fmaf(eb.w, (&w[7].x)[c], a);
        acc[r][c] = a;
      }
    }
  }
  if (valid) {
#pragma unroll
    for (int r = 0; r < 4; ++r) {
      float4 o = make_float4(acc[r][0], acc[r][1], acc[r][2], acc[r][3]);
      *reinterpret_cast<float4*>(&logits[(size_t)(rb + r) * VOCAB + c0]) = o;
    }
  }
#pragma unroll
  for (int r = 0; r < 4; ++r) {
    float m = valid ? fmaxf(fmaxf(acc[r][0], acc[r][1]), fmaxf(acc[r][2], acc[r][3]))
                    : -INFINITY;
#pragma unroll
    for (int o = 32; o >= 1; o >>= 1) m = fmaxf(m, __shfl_xor(m, o));
    float sv = 0.f;
    if (valid && m != -INFINITY) {
      sv = expf(acc[r][0] - m) + expf(acc[r][1] - m) +
           expf(acc[r][2] - m) + expf(acc[r][3] - m);
    }
#pragma unroll
    for (int o = 32; o >= 1; o >>= 1) sv += __shfl_xor(sv, o);
    if (lane == 0) {
      pm[(size_t)(rb + r) * NPART + blockIdx.x] = m;
      ps[(size_t)(rb + r) * NPART + blockIdx.x] = sv;
    }
  }
}

// r16 flat-Wout logits kernel (fallback if ws can't hold the tile) — verbatim.
__global__ __launch_bounds__(512) void k_logits_flat(
    const float* __restrict__ Wout, const float* __restrict__ eg,
    float* __restrict__ logits, float* __restrict__ pm, float* __restrict__ ps) {
  int tid = threadIdx.x;
  int lane = tid & 63, wq = tid >> 6;
  int c0 = blockIdx.x * CBLK + lane * 4;
  bool valid = (c0 + 3 < VOCAB);
  const float* wbase = Wout + (valid ? c0 : (VOCAB - 4));
  int rb = __builtin_amdgcn_readfirstlane(wq) * 4;
  const float* e0 = eg + (size_t)rb * DM;
  float acc[4][4];
#pragma unroll
  for (int r = 0; r < 4; ++r)
#pragma unroll
    for (int c = 0; c < 4; ++c) acc[r][c] = 0.f;
  for (int d = 0; d < DM; d += 8) {
    float4 w[8];
#pragma unroll
    for (int j = 0; j < 8; ++j)
      w[j] = *reinterpret_cast<const float4*>(wbase + (size_t)(d + j) * VOCAB);
#pragma unroll
    for (int r = 0; r < 4; ++r) {
      const float* ep = e0 + r * DM + d;
      const float4 ea = *reinterpret_cast<const float4*>(ep);
      const float4 eb = *reinterpret_cast<const float4*>(ep + 4);
#pragma unroll
      for (int c = 0; c < 4; ++c) {
        float a = acc[r][c];
        a = fmaf(ea.x, (&w[0].x)[c], a);
        a = fmaf(ea.y, (&w[1].x)[c], a);
        a = fmaf(ea.z, (&w[2].x)[c], a);
        a = fmaf(ea.w, (&w[3].x)[c], a);
        a = fmaf(eb.x, (&w[4].x)[c], a);
        a = fmaf(eb.y, (&w[5].x)[c], a);
        a = fmaf(eb.z, (&w[6].x)[c], a);
        a = fmaf(eb.w, (&w[7].x)[c], a);
        acc[r][c] = a;
      }
    }
  }
  if (valid) {
#pragma unroll
    for (int r = 0; r < 4; ++r) {
      float4 o = make_float4(acc[r][0], acc[r][1], acc[r][2], acc[r][3]);
      *reinterpret_cast<float4*>(&logits[(size_t)(rb + r) * VOCAB + c0]) = o;
    }
  }
#pragma unroll
  for (int r = 0; r < 4; ++r) {
    float m = valid ? fmaxf(fmaxf(acc[r][0], acc[r][1]), fmaxf(acc[r][2], acc[r][3]))
                    : -INFINITY;
#pragma unroll
    for (int o = 32; o >= 1; o >>= 1) m = fmaxf(m, __shfl_xor(m, o));
    float sv = 0.f;
    if (valid && m != -INFINITY) {
      sv = expf(acc[r][0] - m) + expf(acc[r][1] - m) +
           expf(acc[r][2] - m) + expf(acc[r][3] - m);
    }
#pragma unroll
    for (int o = 32; o >= 1; o >>= 1) sv += __shfl_xor(sv, o);
    if (lane == 0) {
      pm[(size_t)(rb + r) * NPART + blockIdx.x] = m;
      ps[(size_t)(rb + r) * NPART + blockIdx.x] = sv;
    }
  }
}

// Stage 1 (NEW, r14-proven key decomposition): grid NB*NK*NCH = 1568, 256 thr.
// One (batch, beam, 1024-col chunk) per block. Rank by key = logit - 0.5*pen
// (EXACT in f32; lse/gs-free since per-row ranking is monotone in key — the
// exact rescore happens in s2 with the proven reconstruction chain).
// Tie-break: col ascending. Output: 4 (key, col|pen<<16) per block.
__global__ __launch_bounds__(256) void k_topk_s1(
    const float* __restrict__ logits, const int* __restrict__ minpos,
    float* __restrict__ s1v, int* __restrict__ s1i, int t, int g) {
  int blk = blockIdx.x;
  int b = blk / (NK * NCH);
  int k = (blk / NCH) % NK;
  int c = blk % NCH;
  int tid = threadIdx.x;
  __shared__ float lv[256][4];
  __shared__ int li[256][4];

  const float* lrow = logits + (size_t)(b * NK + k) * VOCAB;
  const int* mp = minpos + (size_t)k * VOCAB;

  float tv[4]; int ti[4];
#pragma unroll
  for (int j = 0; j < 4; ++j) { tv[j] = -INFINITY; ti[j] = CINV; }

  int v = c * SCH + tid * 4;
  if (v + 3 < VOCAB) {
    float4 x4 = *reinterpret_cast<const float4*>(lrow + v);
    float xs[4] = {x4.x, x4.y, x4.z, x4.w};
    int pen[4] = {0, 0, 0, 0};
    if (g) {
      int4 m4 = *reinterpret_cast<const int4*>(mp + v);
      pen[0] = m4.x < t; pen[1] = m4.y < t; pen[2] = m4.z < t; pen[3] = m4.w < t;
    }
#pragma unroll
    for (int i = 0; i < 4; ++i) {
      float key = xs[i] - (pen[i] ? 0.5f : 0.0f);   // exact
      int col = v + i;
      int vp = col | (pen[i] << 16);
      if (cbetter(key, col, tv[3], ti[3] & 0xFFFF)) {
        int pos = 3;
        if (cbetter(key, col, tv[2], ti[2] & 0xFFFF)) { tv[3]=tv[2]; ti[3]=ti[2]; pos=2;
          if (cbetter(key, col, tv[1], ti[1] & 0xFFFF)) { tv[2]=tv[1]; ti[2]=ti[1]; pos=1;
            if (cbetter(key, col, tv[0], ti[0] & 0xFFFF)) { tv[1]=tv[0]; ti[1]=ti[0]; pos=0; } } }
        tv[pos] = key; ti[pos] = vp;
      }
    }
  } else {
#pragma unroll
    for (int i = 0; i < 4; ++i) {
      int vv = v + i;
      if (vv >= VOCAB) break;
      int pen = (g && mp[vv] < t) ? 1 : 0;
      float key = lrow[vv] - (pen ? 0.5f : 0.0f);
      int vp = vv | (pen << 16);
      if (cbetter(key, vv, tv[3], ti[3] & 0xFFFF)) {
        int pos = 3;
        if (cbetter(key, vv, tv[2], ti[2] & 0xFFFF)) { tv[3]=tv[2]; ti[3]=ti[2]; pos=2;
          if (cbetter(key, vv, tv[1], ti[1] & 0xFFFF)) { tv[2]=tv[1]; ti[2]=ti[1]; pos=1;
            if (cbetter(key, vv, tv[0], ti[0] & 0xFFFF)) { tv[1]=tv[0]; ti[1]=ti[0]; pos=0; } } }
        tv[pos] = key; ti[pos] = vp;
      }
    }
  }
#pragma unroll
  for (int j = 0; j < 4; ++j) { lv[tid][j] = tv[j]; li[tid][j] = ti[j]; }
  __syncthreads();
  for (int s = 128; s >= 1; s >>= 1) {
    if (tid < s) {
      float av[4], bv[4], rv[4]; int ai[4], bi[4], ri[4];
#pragma unroll
      for (int j = 0; j < 4; ++j) { av[j]=lv[tid][j]; ai[j]=li[tid][j]; bv[j]=lv[tid+s][j]; bi[j]=li[tid+s][j]; }
      merge4c(av, ai, bv, bi, rv, ri);
#pragma unroll
      for (int j = 0; j < 4; ++j) { lv[tid][j]=rv[j]; li[tid][j]=ri[j]; }
    }
    __syncthreads();
  }
  if (tid == 0) {
    // layout: (b*NK + k)*196 + c*4 + j
    size_t base = ((size_t)(b * NK + k) * NCH + c) * 4;
#pragma unroll
    for (int j = 0; j < 4; ++j) {
      s1v[base + j] = lv[0][j];
      s1i[base + j] = li[0][j];
    }
  }
}

// Stage 2 (NEW): grid NB, 256 thr. lse combine (r16 verbatim, wave w -> row w),
// exact rescore of NK*NCH*4 = 784 candidates with the PROVEN reconstruction
// chain (r14/r16), 256-thread LDS tree -> top-4, seq update, out, next-step eg.
__global__ __launch_bounds__(256) void k_topk_s2(
    const float* __restrict__ s1v, const int* __restrict__ s1i,
    const float* __restrict__ pm, const float* __restrict__ ps,
    const float* __restrict__ gs_src, const int* __restrict__ seq_src,
    const float* __restrict__ Emb, const float* __restrict__ ctx,
    float* __restrict__ gs_dst, int* __restrict__ seq_dst,
    float* __restrict__ eg, int t, int g, float* __restrict__ out) {
  int b = blockIdx.x, tid = threadIdx.x;
  int lane = tid & 63, wave = tid >> 6;
  __shared__ float gsv[NK], lsev[NK];
  __shared__ float lv[256][4];
  __shared__ int li[256][4];
  __shared__ int oldseq[NK * SL];
  __shared__ float selv[NK];
  __shared__ int selb[NK], selt[NK];
  if (tid < NK) gsv[tid] = gs_src[b * NK + tid];
  if (tid < NK * SL) oldseq[tid] = seq_src[b * NK * SL + tid];
  {
    int row = b * NK + wave;
    const float* pmr = pm + (size_t)row * NPART;
    const float* psr = ps + (size_t)row * NPART;
    float M = -INFINITY, S = 0.f;
    for (int j = lane; j < NPART; j += 64) {
      float mj = pmr[j];
      if (mj != -INFINITY) {
        float sj = psr[j];
        float Mn = fmaxf(M, mj);
        S = (M == -INFINITY) ? sj * expf(mj - Mn)
                             : S * expf(M - Mn) + sj * expf(mj - Mn);
        M = Mn;
      }
    }
#pragma unroll
    for (int o = 32; o >= 1; o >>= 1) {
      float Mo = __shfl_xor(M, o);
      float So = __shfl_xor(S, o);
      if (Mo != -INFINITY) {
        float Mn = fmaxf(M, Mo);
        S = (M == -INFINITY) ? So * expf(Mo - Mn)
                             : S * expf(M - Mn) + So * expf(Mo - Mn);
        M = Mn;
      }
    }
    if (lane == 0) lsev[wave] = M + logf(S);
  }
  __syncthreads();

  float tv[4]; int ti[4];
#pragma unroll
  for (int j = 0; j < 4; ++j) { tv[j] = -INFINITY; ti[j] = CINV; }
  const int PERROW = NCH * 4;   // 196 candidates per row
  for (int cc = tid; cc < NK * PERROW; cc += 256) {
    int r = cc / PERROW, e = cc - r * PERROW;
    size_t addr = (size_t)(b * NK + r) * PERROW + e;
    float key = s1v[addr];
    int vp = s1i[addr];
    if (vp == CINV) continue;
    int pen = (vp >> 16) & 1;
    int col = vp & 0xFFFF;
    float l = key + (pen ? 0.5f : 0.0f);   // exact logit reconstruction
    float sc = l - lsev[r];                // ref rounding
    if (pen) sc -= DIVS;                   // ref rounding
    float x = gsv[r] + sc;                 // ref rounding
    int idx = r * VOCAB + col;
    if (cbetter(x, idx, tv[3], ti[3])) {
      int pos = 3;
      if (cbetter(x, idx, tv[2], ti[2])) { tv[3]=tv[2]; ti[3]=ti[2]; pos=2;
        if (cbetter(x, idx, tv[1], ti[1])) { tv[2]=tv[1]; ti[2]=ti[1]; pos=1;
          if (cbetter(x, idx, tv[0], ti[0])) { tv[1]=tv[0]; ti[1]=ti[0]; pos=0; } } }
      tv[pos] = x; ti[pos] = idx;
    }
  }
#pragma unroll
  for (int j = 0; j < 4; ++j) { lv[tid][j] = tv[j]; li[tid][j] = ti[j]; }
  __syncthreads();
  for (int s = 128; s >= 1; s >>= 1) {
    if (tid < s) {
      float av[4], bv[4], rv[4]; int ai[4], bi[4], ri[4];
#pragma unroll
      for (int j = 0; j < 4; ++j) { av[j]=lv[tid][j]; ai[j]=li[tid][j]; bv[j]=lv[tid+s][j]; bi[j]=li[tid+s][j]; }
      merge4(av, ai, bv, bi, rv, ri);
#pragma unroll
      for (int j = 0; j < 4; ++j) { lv[tid][j]=rv[j]; li[tid][j]=ri[j]; }
    }
    __syncthreads();
  }
  if (tid == 0) {
#pragma unroll
    for (int j = 0; j < 4; ++j) {
      selv[j] = lv[0][j];
      selb[j] = li[0][j] / VOCAB;
      selt[j] = li[0][j] % VOCAB;
    }
  }
  __syncthreads();
  if (tid < NK * SL) {
    int j = tid / SL, l = tid % SL;
    int tok = (l == t) ? selt[j] : oldseq[selb[j] * SL + l];
    seq_dst[b * NK * SL + tid] = tok;
    if (t == SL - 1) out[(size_t)b * (2 * NK * SL) + (g * NK + j) * SL + l] = (float)tok;
  }
  if (tid < NK) {
    gs_dst[b * NK + tid] = selv[tid];
    if (t == SL - 1) out[NB * 2 * NK * SL + b * (2 * NK) + g * NK + tid] = selv[tid];
  }
  if (t < SL - 1) {
    int d = tid;  // 256 threads == DM
#pragma unroll
    for (int j = 0; j < NK; ++j) {
      int nt_ = selt[j];
      eg[(size_t)(b * NK + j) * DM + d] = Emb[(size_t)nt_ * DM + d] + ctx[b * DM + d];
    }
  }
}

__global__ void k_init(int* __restrict__ seqA, float* __restrict__ gsA) {
  int i = threadIdx.x;  // 768 threads
  seqA[i] = (i % SL == 0) ? 1 : 0;
  if (i < NB * NK) gsA[i] = ((i & 3) == 0) ? 0.f : -1e9f;
}

__global__ void k_minpos_init(int* __restrict__ minpos) {
  int i = blockIdx.x * 256 + threadIdx.x;
  if (i < NK * VOCAB) minpos[i] = 1 << 30;
}

__global__ void k_minpos_scatter(const int* __restrict__ seq, int* __restrict__ minpos) {
  int i = threadIdx.x;  // 768 threads
  int l = i % SL;
  int k = (i / SL) % NK;
  int tok = seq[i];
  atomicMin(&minpos[(size_t)k * VOCAB + tok], l);
}

extern "C" void kernel_launch(void* const* d_in, const int* in_sizes, int n_in,
                              void* d_out, int out_size, void* d_ws, size_t ws_size,
                              hipStream_t stream) {
  (void)in_sizes; (void)n_in; (void)out_size;
  const float* src  = (const float*)d_in[0];
  const float* We   = (const float*)d_in[1];
  const float* Emb  = (const float*)d_in[2];
  const float* Wout = (const float*)d_in[3];
  float* out = (float*)d_out;
  char* ws = (char*)d_ws;
  size_t off = 0;
  auto carve = [&](size_t bytes) {
    char* p = ws + off;
    off += (bytes + 255) & ~(size_t)255;
    return p;
  };
  float* ctx    = (float*)carve((size_t)NB * DM * 4);
  float* eg     = (float*)carve((size_t)NROW * DM * 4);
  float* logits = (float*)carve((size_t)NROW * VOCAB * 4);
  float* pm     = (float*)carve((size_t)NROW * NPART * 4);
  float* ps     = (float*)carve((size_t)NROW * NPART * 4);
  int*   seqA   = (int*)carve((size_t)NB * NK * SL * 4);
  int*   seqB   = (int*)carve((size_t)NB * NK * SL * 4);
  float* gsA    = (float*)carve((size_t)NROW * 4);
  float* gsB    = (float*)carve((size_t)NROW * 4);
  int*   minpos = (int*)carve((size_t)NK * VOCAB * 4);
  float* s1v    = (float*)carve((size_t)NB * NK * NCH * 4 * 4);
  int*   s1i    = (int*)carve((size_t)NB * NK * NCH * 4 * 4);
  size_t wt_bytes = (size_t)NXB * CBLK * DM * 4;   // 51.4 MB
  bool use_tile = (off + wt_bytes + 256 <= ws_size);
  float* WT = use_tile ? (float*)carve(wt_bytes) : nullptr;

  hipLaunchKernelGGL(k_prep, dim3(NB), dim3(DM), 0, stream, src, We, ctx);
  if (use_tile)
    hipLaunchKernelGGL(k_wtile, dim3(NXB, DM), dim3(CBLK), 0, stream, Wout, WT);

  for (int g = 0; g < 2; ++g) {
    hipLaunchKernelGGL(k_init, dim3(1), dim3(768), 0, stream, seqA, gsA);
    for (int t = 1; t < SL; ++t) {
      int* ssrc = ((t - 1) & 1) ? seqB : seqA;
      int* sdst = (t & 1) ? seqB : seqA;
      float* gsrc = ((t - 1) & 1) ? gsB : gsA;
      float* gdst = (t & 1) ? gsB : gsA;
      if (t == 1)
        hipLaunchKernelGGL(k_eprep, dim3(NROW), dim3(DM), 0, stream,
                           Emb, ctx, ssrc, eg, t);
      if (use_tile)
        hipLaunchKernelGGL(k_logits_tiled, dim3(NXB), dim3(512), 0, stream,
                           WT, eg, logits, pm, ps);
      else
        hipLaunchKernelGGL(k_logits_flat, dim3(NXB), dim3(512), 0, stream,
                           Wout, eg, logits, pm, ps);
      hipLaunchKernelGGL(k_topk_s1, dim3(NB * NK * NCH), dim3(256), 0, stream,
                         logits, minpos, s1v, s1i, t, g);
      hipLaunchKernelGGL(k_topk_s2, dim3(NB), dim3(256), 0, stream,
                         s1v, s1i, pm, ps, gsrc, ssrc, Emb, ctx,
                         gdst, sdst, eg, t, g, out);
    }
    if (g == 0) {
      hipLaunchKernelGGL(k_minpos_init, dim3((NK * VOCAB + 255) / 256), dim3(256), 0, stream, minpos);
      hipLaunchKernelGGL(k_minpos_scatter, dim3(1), dim3(768), 0, stream, seqB, minpos);
    }
  }
}

// Round 22
// 2245.039 us; speedup vs baseline: 1.1190x; 1.1190x over previous
//
#include <hip/hip_runtime.h>
#include <math.h>

#define VOCAB 50000
#define DM 256
#define NB 8
#define NK 4
#define SL 24
#define NROW 32
#define CBLK 256         // columns per block (4 per lane)
#define NXB 196          // ceil(50000/256)
#define NPART NXB        // lse partials per row
#define DIVS 0.5f
#define NCH 49           // selection chunks of 1024
#define SCH 1024

__device__ __forceinline__ bool cbetter(float av, int ai, float bv, int bi) {
  return (av > bv) || (av == bv && ai < bi);
}

__device__ __forceinline__ void merge4(const float* av, const int* ai,
                                       const float* bv, const int* bi,
                                       float* rv, int* ri) {
  int x = 0, y = 0;
#pragma unroll
  for (int j = 0; j < 4; ++j) {
    bool ta = cbetter(av[x], ai[x], bv[y], bi[y]);
    rv[j] = ta ? av[x] : bv[y];
    ri[j] = ta ? ai[x] : bi[y];
    if (ta) ++x; else ++y;
  }
}

// ctx[b][d] = mean_s(src[b,s,:]) @ We
__global__ void k_prep(const float* __restrict__ src, const float* __restrict__ We,
                       float* __restrict__ ctx) {
  int b = blockIdx.x, d = threadIdx.x;
  __shared__ float sm[DM];
  const float* p = src + (size_t)b * 128 * DM + d;
  float s = 0.f;
  for (int i = 0; i < 128; ++i) s += p[i * DM];
  sm[d] = s * (1.f / 128.f);
  __syncthreads();
  float acc = 0.f;
  for (int dp = 0; dp < DM; ++dp) acc += sm[dp] * We[dp * DM + d];
  ctx[b * DM + d] = acc;
}

// eg[r][d] = Emb[tok_r][d] + ctx[r/4][d]   (t==1 only; s2 updates eg after)
__global__ void k_eprep(const float* __restrict__ Emb, const float* __restrict__ ctx,
                        const int* __restrict__ seq, float* __restrict__ eg, int t) {
  int r = blockIdx.x, d = threadIdx.x;
  int tok = seq[r * SL + (t - 1)];
  eg[r * DM + d] = Emb[(size_t)tok * DM + d] + ctx[(r >> 2) * DM + d];
}

// One-time per launch: tile Wout so each logits block reads a CONTIGUOUS
// 256-KB region. WT[b][d][c] = Wout[d][b*256+c] (0 beyond VOCAB).
__global__ void k_wtile(const float* __restrict__ Wout, float* __restrict__ WT) {
  int b = blockIdx.x, d = blockIdx.y, c = threadIdx.x;
  int col = b * CBLK + c;
  WT[(size_t)b * (CBLK * DM) + d * CBLK + c] =
      (col < VOCAB) ? Wout[(size_t)d * VOCAB + col] : 0.f;
}

// Tiled logits kernel: grid 196, 512 thr (8 waves). Wave q -> rows 4q..4q+3;
// lane -> 4 contiguous cols. e is wave-uniform scalar loads. FMA fold
// ascending-d, identical nesting -> bit-identical logits. Emits per-(row,
// 256-col) softmax partials.
__global__ __launch_bounds__(512) void k_logits_tiled(
    const float* __restrict__ WT, const float* __restrict__ eg,
    float* __restrict__ logits, float* __restrict__ pm, float* __restrict__ ps) {
  int tid = threadIdx.x;
  int lane = tid & 63, wq = tid >> 6;
  int c0 = blockIdx.x * CBLK + lane * 4;
  bool valid = (c0 + 3 < VOCAB);
  const float* wbase = WT + (size_t)blockIdx.x * (CBLK * DM) + lane * 4;
  int rb = __builtin_amdgcn_readfirstlane(wq) * 4;
  const float* e0 = eg + (size_t)rb * DM;
  float acc[4][4];
#pragma unroll
  for (int r = 0; r < 4; ++r)
#pragma unroll
    for (int c = 0; c < 4; ++c) acc[r][c] = 0.f;

  for (int d = 0; d < DM; d += 8) {
    float4 w[8];
#pragma unroll
    for (int j = 0; j < 8; ++j)
      w[j] = *reinterpret_cast<const float4*>(wbase + (size_t)(d + j) * CBLK);
#pragma unroll
    for (int r = 0; r < 4; ++r) {
      const float* ep = e0 + r * DM + d;
      const float4 ea = *reinterpret_cast<const float4*>(ep);
      const float4 eb = *reinterpret_cast<const float4*>(ep + 4);
#pragma unroll
      for (int c = 0; c < 4; ++c) {
        float a = acc[r][c];
        a = fmaf(ea.x, (&w[0].x)[c], a);
        a = fmaf(ea.y, (&w[1].x)[c], a);
        a = fmaf(ea.z, (&w[2].x)[c], a);
        a = fmaf(ea.w, (&w[3].x)[c], a);
        a = fmaf(eb.x, (&w[4].x)[c], a);
        a = fmaf(eb.y, (&w[5].x)[c], a);
        a = fmaf(eb.z, (&w[6].x)[c], a);
        a = fmaf(eb.w, (&w[7].x)[c], a);
        acc[r][c] = a;
      }
    }
  }
  if (valid) {
#pragma unroll
    for (int r = 0; r < 4; ++r) {
      float4 o = make_float4(acc[r][0], acc[r][1], acc[r][2], acc[r][3]);
      *reinterpret_cast<float4*>(&logits[(size_t)(rb + r) * VOCAB + c0]) = o;
    }
  }
#pragma unroll
  for (int r = 0; r < 4; ++r) {
    float m = valid ? fmaxf(fmaxf(acc[r][0], acc[r][1]), fmaxf(acc[r][2], acc[r][3]))
                    : -INFINITY;
#pragma unroll
    for (int o = 32; o >= 1; o >>= 1) m = fmaxf(m, __shfl_xor(m, o));
    float sv = 0.f;
    if (valid && m != -INFINITY) {
      sv = expf(acc[r][0] - m) + expf(acc[r][1] - m) +
           expf(acc[r][2] - m) + expf(acc[r][3] - m);
    }
#pragma unroll
    for (int o = 32; o >= 1; o >>= 1) sv += __shfl_xor(sv, o);
    if (lane == 0) {
      pm[(size_t)(rb + r) * NPART + blockIdx.x] = m;
      ps[(size_t)(rb + r) * NPART + blockIdx.x] = sv;
    }
  }
}

// Flat-Wout logits kernel (fallback if ws can't hold the tile).
__global__ __launch_bounds__(512) void k_logits_flat(
    const float* __restrict__ Wout, const float* __restrict__ eg,
    float* __restrict__ logits, float* __restrict__ pm, float* __restrict__ ps) {
  int tid = threadIdx.x;
  int lane = tid & 63, wq = tid >> 6;
  int c0 = blockIdx.x * CBLK + lane * 4;
  bool valid = (c0 + 3 < VOCAB);
  const float* wbase = Wout + (valid ? c0 : (VOCAB - 4));
  int rb = __builtin_amdgcn_readfirstlane(wq) * 4;
  const float* e0 = eg + (size_t)rb * DM;
  float acc[4][4];
#pragma unroll
  for (int r = 0; r < 4; ++r)
#pragma unroll
    for (int c = 0; c < 4; ++c) acc[r][c] = 0.f;
  for (int d = 0; d < DM; d += 8) {
    float4 w[8];
#pragma unroll
    for (int j = 0; j < 8; ++j)
      w[j] = *reinterpret_cast<const float4*>(wbase + (size_t)(d + j) * VOCAB);
#pragma unroll
    for (int r = 0; r < 4; ++r) {
      const float* ep = e0 + r * DM + d;
      const float4 ea = *reinterpret_cast<const float4*>(ep);
      const float4 eb = *reinterpret_cast<const float4*>(ep + 4);
#pragma unroll
      for (int c = 0; c < 4; ++c) {
        float a = acc[r][c];
        a = fmaf(ea.x, (&w[0].x)[c], a);
        a = fmaf(ea.y, (&w[1].x)[c], a);
        a = fmaf(ea.z, (&w[2].x)[c], a);
        a = fmaf(ea.w, (&w[3].x)[c], a);
        a = fmaf(eb.x, (&w[4].x)[c], a);
        a = fmaf(eb.y, (&w[5].x)[c], a);
        a = fmaf(eb.z, (&w[6].x)[c], a);
        a = fmaf(eb.w, (&w[7].x)[c], a);
        acc[r][c] = a;
      }
    }
  }
  if (valid) {
#pragma unroll
    for (int r = 0; r < 4; ++r) {
      float4 o = make_float4(acc[r][0], acc[r][1], acc[r][2], acc[r][3]);
      *reinterpret_cast<float4*>(&logits[(size_t)(rb + r) * VOCAB + c0]) = o;
    }
  }
#pragma unroll
  for (int r = 0; r < 4; ++r) {
    float m = valid ? fmaxf(fmaxf(acc[r][0], acc[r][1]), fmaxf(acc[r][2], acc[r][3]))
                    : -INFINITY;
#pragma unroll
    for (int o = 32; o >= 1; o >>= 1) m = fmaxf(m, __shfl_xor(m, o));
    float sv = 0.f;
    if (valid && m != -INFINITY) {
      sv = expf(acc[r][0] - m) + expf(acc[r][1] - m) +
           expf(acc[r][2] - m) + expf(acc[r][3] - m);
    }
#pragma unroll
    for (int o = 32; o >= 1; o >>= 1) sv += __shfl_xor(sv, o);
    if (lane == 0) {
      pm[(size_t)(rb + r) * NPART + blockIdx.x] = m;
      ps[(size_t)(rb + r) * NPART + blockIdx.x] = sv;
    }
  }
}

// Stage 1: grid (NB*NCH), 256 thr. Combine LSE partials (wave w -> row w), then
// per-thread sorted-4 over a 1024-wide chunk (exact ref per-candidate
// arithmetic), then 8-level LDS merge tree -> chunk top-4.
__global__ __launch_bounds__(256) void k_topk_s1(
    const float* __restrict__ logits, const float* __restrict__ pm,
    const float* __restrict__ ps, const float* __restrict__ gs_src,
    const int* __restrict__ minpos, float* __restrict__ s1v,
    int* __restrict__ s1i, int t, int g) {
  int b = blockIdx.x / NCH, c = blockIdx.x % NCH, tid = threadIdx.x;
  int lane = tid & 63, wave = tid >> 6;
  __shared__ float gsv[NK], lsev[NK];
  __shared__ float lv[256][4];
  __shared__ int li[256][4];
  if (tid < NK) gsv[tid] = gs_src[b * NK + tid];
  {
    int row = b * NK + wave;
    const float* pmr = pm + (size_t)row * NPART;
    const float* psr = ps + (size_t)row * NPART;
    float M = -INFINITY, S = 0.f;
    for (int j = lane; j < NPART; j += 64) {
      float mj = pmr[j];
      if (mj != -INFINITY) {
        float sj = psr[j];
        float Mn = fmaxf(M, mj);
        S = (M == -INFINITY) ? sj * expf(mj - Mn)
                             : S * expf(M - Mn) + sj * expf(mj - Mn);
        M = Mn;
      }
    }
#pragma unroll
    for (int o = 32; o >= 1; o >>= 1) {
      float Mo = __shfl_xor(M, o);
      float So = __shfl_xor(S, o);
      if (Mo != -INFINITY) {
        float Mn = fmaxf(M, Mo);
        S = (M == -INFINITY) ? So * expf(Mo - Mn)
                             : S * expf(M - Mn) + So * expf(Mo - Mn);
        M = Mn;
      }
    }
    if (lane == 0) lsev[wave] = M + logf(S);
  }
  __syncthreads();

  float tv[4]; int ti[4];
#pragma unroll
  for (int j = 0; j < 4; ++j) { tv[j] = -INFINITY; ti[j] = 0x7fffffff; }

  int v = c * SCH + tid * 4;
  for (int k = 0; k < NK; ++k) {
    float gsk = gsv[k], lsek = lsev[k];
    const float* lrow = logits + (size_t)(b * NK + k) * VOCAB;
    const int* mp = minpos + (size_t)k * VOCAB;
    if (v + 3 < VOCAB) {
      float4 x4 = *reinterpret_cast<const float4*>(lrow + v);
      float xs[4] = {x4.x, x4.y, x4.z, x4.w};
      int pen[4] = {0, 0, 0, 0};
      if (g) {
        int4 m4 = *reinterpret_cast<const int4*>(mp + v);
        pen[0] = m4.x < t; pen[1] = m4.y < t; pen[2] = m4.z < t; pen[3] = m4.w < t;
      }
#pragma unroll
      for (int i = 0; i < 4; ++i) {
        float sc = xs[i] - lsek;
        if (pen[i]) sc -= DIVS;
        float x = gsk + sc;
        int idx = k * VOCAB + v + i;
        if (cbetter(x, idx, tv[3], ti[3])) {
          int pos = 3;
          if (cbetter(x, idx, tv[2], ti[2])) { tv[3]=tv[2]; ti[3]=ti[2]; pos=2;
            if (cbetter(x, idx, tv[1], ti[1])) { tv[2]=tv[1]; ti[2]=ti[1]; pos=1;
              if (cbetter(x, idx, tv[0], ti[0])) { tv[1]=tv[0]; ti[1]=ti[0]; pos=0; } } }
          tv[pos] = x; ti[pos] = idx;
        }
      }
    } else {
#pragma unroll
      for (int i = 0; i < 4; ++i) {
        int vv = v + i;
        if (vv >= VOCAB) break;
        float sc = lrow[vv] - lsek;
        if (g && mp[vv] < t) sc -= DIVS;
        float x = gsk + sc;
        int idx = k * VOCAB + vv;
        if (cbetter(x, idx, tv[3], ti[3])) {
          int pos = 3;
          if (cbetter(x, idx, tv[2], ti[2])) { tv[3]=tv[2]; ti[3]=ti[2]; pos=2;
            if (cbetter(x, idx, tv[1], ti[1])) { tv[2]=tv[1]; ti[2]=ti[1]; pos=1;
              if (cbetter(x, idx, tv[0], ti[0])) { tv[1]=tv[0]; ti[1]=ti[0]; pos=0; } } }
          tv[pos] = x; ti[pos] = idx;
        }
      }
    }
  }
#pragma unroll
  for (int j = 0; j < 4; ++j) { lv[tid][j] = tv[j]; li[tid][j] = ti[j]; }
  __syncthreads();
  for (int s = 128; s >= 1; s >>= 1) {
    if (tid < s) {
      float av[4], bv[4], rv[4]; int ai[4], bi[4], ri[4];
#pragma unroll
      for (int j = 0; j < 4; ++j) { av[j]=lv[tid][j]; ai[j]=li[tid][j]; bv[j]=lv[tid+s][j]; bi[j]=li[tid+s][j]; }
      merge4(av, ai, bv, bi, rv, ri);
#pragma unroll
      for (int j = 0; j < 4; ++j) { lv[tid][j]=rv[j]; li[tid][j]=ri[j]; }
    }
    __syncthreads();
  }
  if (tid == 0) {
#pragma unroll
    for (int j = 0; j < 4; ++j) {
      s1v[(b * NCH + c) * 4 + j] = lv[0][j];
      s1i[(b * NCH + c) * 4 + j] = li[0][j];
    }
  }
}

// Stage 2: grid NB, 256 thr. Merge 49 sorted-4 lists -> top-4, seq update,
// out writes, and next-step eg = Emb[tok]+ctx.
__global__ __launch_bounds__(256) void k_topk_s2(
    const float* __restrict__ s1v, const int* __restrict__ s1i,
    const int* __restrict__ seq_src, const float* __restrict__ Emb,
    const float* __restrict__ ctx, float* __restrict__ gs_dst,
    int* __restrict__ seq_dst, float* __restrict__ eg,
    int t, int g, float* __restrict__ out) {
  int b = blockIdx.x, tid = threadIdx.x;
  __shared__ float lv[64][4];
  __shared__ int li[64][4];
  __shared__ int oldseq[NK * SL];
  __shared__ float selv[NK];
  __shared__ int selb[NK], selt[NK];
  if (tid < 64) {
#pragma unroll
    for (int j = 0; j < 4; ++j) {
      if (tid < NCH) { lv[tid][j] = s1v[(b * NCH + tid) * 4 + j]; li[tid][j] = s1i[(b * NCH + tid) * 4 + j]; }
      else { lv[tid][j] = -INFINITY; li[tid][j] = 0x7fffffff; }
    }
  }
  if (tid < NK * SL) oldseq[tid] = seq_src[b * NK * SL + tid];
  __syncthreads();
  for (int s = 32; s >= 1; s >>= 1) {
    if (tid < s) {
      float av[4], bv[4], rv[4]; int ai[4], bi[4], ri[4];
#pragma unroll
      for (int j = 0; j < 4; ++j) { av[j]=lv[tid][j]; ai[j]=li[tid][j]; bv[j]=lv[tid+s][j]; bi[j]=li[tid+s][j]; }
      merge4(av, ai, bv, bi, rv, ri);
#pragma unroll
      for (int j = 0; j < 4; ++j) { lv[tid][j]=rv[j]; li[tid][j]=ri[j]; }
    }
    __syncthreads();
  }
  if (tid == 0) {
#pragma unroll
    for (int j = 0; j < 4; ++j) {
      selv[j] = lv[0][j];
      selb[j] = li[0][j] / VOCAB;
      selt[j] = li[0][j] % VOCAB;
    }
  }
  __syncthreads();
  if (tid < NK * SL) {
    int j = tid / SL, l = tid % SL;
    int tok = (l == t) ? selt[j] : oldseq[selb[j] * SL + l];
    seq_dst[b * NK * SL + tid] = tok;
    if (t == SL - 1) out[(size_t)b * (2 * NK * SL) + (g * NK + j) * SL + l] = (float)tok;
  }
  if (tid < NK) {
    gs_dst[b * NK + tid] = selv[tid];
    if (t == SL - 1) out[NB * 2 * NK * SL + b * (2 * NK) + g * NK + tid] = selv[tid];
  }
  if (t < SL - 1) {
    int d = tid;  // 256 threads == DM
#pragma unroll
    for (int j = 0; j < NK; ++j) {
      int nt_ = selt[j];
      eg[(size_t)(b * NK + j) * DM + d] = Emb[(size_t)nt_ * DM + d] + ctx[b * DM + d];
    }
  }
}

__global__ void k_init(int* __restrict__ seqA, float* __restrict__ gsA) {
  int i = threadIdx.x;  // 768 threads
  seqA[i] = (i % SL == 0) ? 1 : 0;
  if (i < NB * NK) gsA[i] = ((i & 3) == 0) ? 0.f : -1e9f;
}

__global__ void k_minpos_init(int* __restrict__ minpos) {
  int i = blockIdx.x * 256 + threadIdx.x;
  if (i < NK * VOCAB) minpos[i] = 1 << 30;
}

__global__ void k_minpos_scatter(const int* __restrict__ seq, int* __restrict__ minpos) {
  int i = threadIdx.x;  // 768 threads
  int l = i % SL;
  int k = (i / SL) % NK;
  int tok = seq[i];
  atomicMin(&minpos[(size_t)k * VOCAB + tok], l);
}

extern "C" void kernel_launch(void* const* d_in, const int* in_sizes, int n_in,
                              void* d_out, int out_size, void* d_ws, size_t ws_size,
                              hipStream_t stream) {
  (void)in_sizes; (void)n_in; (void)out_size;
  const float* src  = (const float*)d_in[0];
  const float* We   = (const float*)d_in[1];
  const float* Emb  = (const float*)d_in[2];
  const float* Wout = (const float*)d_in[3];
  float* out = (float*)d_out;
  char* ws = (char*)d_ws;
  size_t off = 0;
  auto carve = [&](size_t bytes) {
    char* p = ws + off;
    off += (bytes + 255) & ~(size_t)255;
    return p;
  };
  float* ctx    = (float*)carve((size_t)NB * DM * 4);
  float* eg     = (float*)carve((size_t)NROW * DM * 4);
  float* logits = (float*)carve((size_t)NROW * VOCAB * 4);
  float* pm     = (float*)carve((size_t)NROW * NPART * 4);
  float* ps     = (float*)carve((size_t)NROW * NPART * 4);
  int*   seqA   = (int*)carve((size_t)NB * NK * SL * 4);
  int*   seqB   = (int*)carve((size_t)NB * NK * SL * 4);
  float* gsA    = (float*)carve((size_t)NROW * 4);
  float* gsB    = (float*)carve((size_t)NROW * 4);
  int*   minpos = (int*)carve((size_t)NK * VOCAB * 4);
  float* s1v    = (float*)carve((size_t)NB * NCH * 4 * 4);
  int*   s1i    = (int*)carve((size_t)NB * NCH * 4 * 4);
  size_t wt_bytes = (size_t)NXB * CBLK * DM * 4;   // 51.4 MB
  bool use_tile = (off + wt_bytes + 256 <= ws_size);
  float* WT = use_tile ? (float*)carve(wt_bytes) : nullptr;

  hipLaunchKernelGGL(k_prep, dim3(NB), dim3(DM), 0, stream, src, We, ctx);
  if (use_tile)
    hipLaunchKernelGGL(k_wtile, dim3(NXB, DM), dim3(CBLK), 0, stream, Wout, WT);

  for (int g = 0; g < 2; ++g) {
    hipLaunchKernelGGL(k_init, dim3(1), dim3(768), 0, stream, seqA, gsA);
    for (int t = 1; t < SL; ++t) {
      int* ssrc = ((t - 1) & 1) ? seqB : seqA;
      int* sdst = (t & 1) ? seqB : seqA;
      float* gsrc = ((t - 1) & 1) ? gsB : gsA;
      float* gdst = (t & 1) ? gsB : gsA;
      if (t == 1)
        hipLaunchKernelGGL(k_eprep, dim3(NROW), dim3(DM), 0, stream,
                           Emb, ctx, ssrc, eg, t);
      if (use_tile)
        hipLaunchKernelGGL(k_logits_tiled, dim3(NXB), dim3(512), 0, stream,
                           WT, eg, logits, pm, ps);
      else
        hipLaunchKernelGGL(k_logits_flat, dim3(NXB), dim3(512), 0, stream,
                           Wout, eg, logits, pm, ps);
      hipLaunchKernelGGL(k_topk_s1, dim3(NB * NCH), dim3(256), 0, stream,
                         logits, pm, ps, gsrc, minpos, s1v, s1i, t, g);
      hipLaunchKernelGGL(k_topk_s2, dim3(NB), dim3(256), 0, stream,
                         s1v, s1i, ssrc, Emb, ctx, gdst, sdst, eg, t, g, out);
    }
    if (g == 0) {
      hipLaunchKernelGGL(k_minpos_init, dim3((NK * VOCAB + 255) / 256), dim3(256), 0, stream, minpos);
      hipLaunchKernelGGL(k_minpos_scatter, dim3(1), dim3(768), 0, stream, seqB, minpos);
    }
  }
}